// Round 6
// baseline (370.210 us; speedup 1.0000x reference)
//
#include <hip/hip_runtime.h>

#define D_DIM 1024
#define F_DIM 4096
#define E_NUM 16
#define T_NUM 2048

typedef __bf16 bf16x8 __attribute__((ext_vector_type(8)));
typedef float f32x4 __attribute__((ext_vector_type(4)));

__device__ __forceinline__ unsigned pack2bf(float a, float b) {
  unsigned ua = __builtin_bit_cast(unsigned, a);
  unsigned ub = __builtin_bit_cast(unsigned, b);
  return ((ub + 0x8000u) & 0xffff0000u) | ((ua + 0x8000u) >> 16);
}
__device__ __forceinline__ unsigned short f2bf(float a) {
  unsigned ua = __builtin_bit_cast(unsigned, a);
  return (unsigned short)((ua + 0x8000u) >> 16);
}
__device__ __forceinline__ bf16x8 cvt8(f32x4 a, f32x4 b) {
  bf16x8 r;
  r[0] = (__bf16)a[0]; r[1] = (__bf16)a[1]; r[2] = (__bf16)a[2]; r[3] = (__bf16)a[3];
  r[4] = (__bf16)b[0]; r[5] = (__bf16)b[1]; r[6] = (__bf16)b[2]; r[7] = (__bf16)b[3];
  return r;
}
__device__ __forceinline__ void gload16(const void* g, void* l) {
  __builtin_amdgcn_global_load_lds(
      (const __attribute__((address_space(1))) unsigned*)g,
      (__attribute__((address_space(3))) unsigned*)l, 16, 0, 0);
}

// ---------------- x -> bf16 pre-pass
__global__ __launch_bounds__(256) void moe_xcast(
    const float* __restrict__ x, unsigned short* __restrict__ xbf)
{
  int i = blockIdx.x * 256 + threadIdx.x;
  const f32x4* p = (const f32x4*)x + (size_t)i * 2;
  f32x4 a = p[0], b = p[1];
  uint4 o;
  o.x = pack2bf(a[0], a[1]); o.y = pack2bf(a[2], a[3]);
  o.z = pack2bf(b[0], b[1]); o.w = pack2bf(b[2], b[3]);
  ((uint4*)xbf)[i] = o;
}

// ---------------- router
__global__ __launch_bounds__(256) void moe_router(
    const float* __restrict__ x, const float* __restrict__ gate,
    float* __restrict__ logits_out, int* __restrict__ topi, float* __restrict__ topw)
{
  __shared__ float lg[16][17];
  int tid = threadIdx.x;
  int tbase = blockIdx.x * 16;
  int tt = tid >> 4, e = tid & 15;
  const float4* xr = (const float4*)(x + (size_t)(tbase + tt) * D_DIM);
  const float4* gw = (const float4*)(gate + (size_t)e * D_DIM);
  float acc = 0.f;
  #pragma unroll 4
  for (int k = 0; k < D_DIM / 4; ++k) {
    float4 a = xr[k], b = gw[k];
    acc += a.x * b.x + a.y * b.y + a.z * b.z + a.w * b.w;
  }
  lg[tt][e] = acc;
  logits_out[(size_t)(tbase + tt) * E_NUM + e] = acc;
  __syncthreads();
  if (tid < 16) {
    int t = tid;
    float best = -1e30f; int i0 = 0;
    #pragma unroll
    for (int j = 0; j < 16; ++j) { float v = lg[t][j]; if (v > best) { best = v; i0 = j; } }
    float best1 = -1e30f; int i1 = 0;
    #pragma unroll
    for (int j = 0; j < 16; ++j) { if (j == i0) continue; float v = lg[t][j]; if (v > best1) { best1 = v; i1 = j; } }
    float e1 = __expf(best1 - best);
    float inv = 1.f / (1.f + e1);
    int gt = tbase + t;
    topi[gt * 2]     = i0;  topi[gt * 2 + 1] = i1;
    topw[gt * 2]     = inv; topw[gt * 2 + 1] = e1 * inv;
  }
}

// ---------------- deterministic routing
__global__ __launch_bounds__(1024) void moe_route_build(
    const int* __restrict__ topi,
    int* __restrict__ cnt, int* __restrict__ rowbase,
    int* __restrict__ rowlist, int* __restrict__ rowpos)
{
  __shared__ int scnt[16];
  __shared__ int sbase[17];
  int wave = threadIdx.x >> 6;
  int lane = threadIdx.x & 63;
  int total = 0;
  for (int c = 0; c < (T_NUM * 2) / 64; ++c) {
    int s = c * 64 + lane;
    unsigned long long m = __ballot(topi[s] == wave);
    total += __popcll(m);
  }
  if (lane == 0) scnt[wave] = total;
  __syncthreads();
  if (threadIdx.x == 0) {
    int acc = 0;
    for (int e2 = 0; e2 < 16; ++e2) { sbase[e2] = acc; cnt[e2] = scnt[e2]; acc += scnt[e2]; }
    sbase[16] = acc;
    for (int e2 = 0; e2 <= 16; ++e2) rowbase[e2] = sbase[e2];
  }
  __syncthreads();
  int running = sbase[wave];
  for (int c = 0; c < (T_NUM * 2) / 64; ++c) {
    int s = c * 64 + lane;
    int ei = topi[s];
    unsigned long long m = __ballot(ei == wave);
    if (ei == wave) {
      int pos = running + __popcll(m & ((1ull << lane) - 1ull));
      rowlist[pos] = s;
      rowpos[s] = pos;
    }
    running += __popcll(m);
  }
}

// ---------------- GEMM1: H = silu(x@w1^T) * (x@w3^T)
// 512 threads (8 waves), BM=128 BN=128 BK=32; LDS 80KB, 2 blocks/CU -> 16 waves/CU.
// Counted-vmcnt double-buffer: STAGE(t+1); vmcnt(5); barrier; compute(t); barrier.
__global__ __launch_bounds__(512, 4) void moe_gemm1(
    const unsigned short* __restrict__ xbf, const float* __restrict__ w1s, const float* __restrict__ w3s,
    const int* __restrict__ cnt, const int* __restrict__ rowbase, const int* __restrict__ rowlist,
    unsigned short* __restrict__ H)
{
  int e = blockIdx.z, mt = blockIdx.y, nt = blockIdx.x;
  int Ne = cnt[e];
  if (mt * 128 >= Ne) return;
  int rbase = rowbase[e];

  __shared__ char smem[81920];

  int tid = threadIdx.x, lane = tid & 63, wave = tid >> 6;

  // X staging: 8 chunks of 1KB (16 rows x 64B); wave owns chunk `wave`.
  // swizzle: slot p holds global k-chunk p^((r>>1)&3)
  int xr = wave * 16 + (lane >> 2);
  {
  }
  int xlr = mt * 128 + xr;
  int xtok = (xlr < Ne) ? (rowlist[rbase + xlr] >> 1) : 0;
  int xc = (lane & 3) ^ ((xr >> 1) & 3);
  const char* px = (const char*)(xbf + (size_t)xtok * D_DIM) + xc * 16;

  // W staging: 16 chunks of 1KB (8 rows x 128B); wave owns chunks wave*2, wave*2+1.
  const float* w1e = w1s + (size_t)e * F_DIM * D_DIM + (size_t)(nt * 128) * D_DIM;
  const float* w3e = w3s + (size_t)e * F_DIM * D_DIM + (size_t)(nt * 128) * D_DIM;
  const char* p1[2]; const char* p3[2];
  #pragma unroll
  for (int it = 0; it < 2; ++it) {
    int r = (wave * 2 + it) * 8 + (lane >> 3);
    int c = (lane & 7) ^ (r & 7);
    p1[it] = (const char*)(w1e + (size_t)r * D_DIM) + c * 16;
    p3[it] = (const char*)(w3e + (size_t)r * D_DIM) + c * 16;
  }

  // compute mapping: 8 waves = 2M x 4N; wave-tile 64x32
  int wm = wave >> 2, wn = wave & 3;
  int lr16 = lane & 15, lq = lane >> 4;

  unsigned offA[4];
  #pragma unroll
  for (int mi = 0; mi < 4; ++mi) {
    int m = wm * 64 + mi * 16 + lr16;
    offA[mi] = (unsigned)(m * 64 + ((lq ^ ((m >> 1) & 3)) * 16));
  }
  unsigned offB[2][2];
  #pragma unroll
  for (int ni = 0; ni < 2; ++ni) {
    int n = wn * 32 + ni * 16 + lr16;
    #pragma unroll
    for (int h = 0; h < 2; ++h)
      offB[ni][h] = (unsigned)(n * 128 + (((lq * 2 + h) ^ (n & 7)) * 16));
  }

  f32x4 acc1[4][2], acc3[4][2];
  #pragma unroll
  for (int i = 0; i < 4; ++i)
    #pragma unroll
    for (int j = 0; j < 2; ++j) { acc1[i][j] = {0.f,0.f,0.f,0.f}; acc3[i][j] = {0.f,0.f,0.f,0.f}; }

  unsigned xdst = (unsigned)(wave * 1024 + lane * 16);
  unsigned wdst = (unsigned)((wave * 2) * 1024 + lane * 16);

  auto STAGE = [&](unsigned bsel, int ks) {
    gload16(px + ks * 64, smem + bsel * 8192 + xdst);
    #pragma unroll
    for (int it = 0; it < 2; ++it) {
      gload16(p1[it] + ks * 128, smem + 16384 + bsel * 16384 + wdst + it * 1024);
      gload16(p3[it] + ks * 128, smem + 49152 + bsel * 16384 + wdst + it * 1024);
    }
  };

  STAGE(0, 0);
  unsigned buf = 0;
  for (int ks = 0; ks < 32; ++ks) {
    if (ks < 31) {
      STAGE(buf ^ 1u, ks + 1);
      asm volatile("s_waitcnt vmcnt(5)" ::: "memory");
    } else {
      asm volatile("s_waitcnt vmcnt(0)" ::: "memory");
    }
    __builtin_amdgcn_s_barrier();
    unsigned xb = buf * 8192;
    unsigned w1b = 16384 + buf * 16384;
    unsigned w3b = 49152 + buf * 16384;
    bf16x8 af[4];
    #pragma unroll
    for (int mi = 0; mi < 4; ++mi)
      af[mi] = *(const bf16x8*)(smem + xb + offA[mi]);
    #pragma unroll
    for (int ni = 0; ni < 2; ++ni) {
      bf16x8 b1 = cvt8(*(const f32x4*)(smem + w1b + offB[ni][0]),
                       *(const f32x4*)(smem + w1b + offB[ni][1]));
      bf16x8 b3 = cvt8(*(const f32x4*)(smem + w3b + offB[ni][0]),
                       *(const f32x4*)(smem + w3b + offB[ni][1]));
      #pragma unroll
      for (int mi = 0; mi < 4; ++mi) {
        acc1[mi][ni] = __builtin_amdgcn_mfma_f32_16x16x32_bf16(af[mi], b1, acc1[mi][ni], 0, 0, 0);
        acc3[mi][ni] = __builtin_amdgcn_mfma_f32_16x16x32_bf16(af[mi], b3, acc3[mi][ni], 0, 0, 0);
      }
    }
    __builtin_amdgcn_s_barrier();
    buf ^= 1u;
  }

  #pragma unroll
  for (int mi = 0; mi < 4; ++mi) {
    int mb = wm * 64 + mi * 16 + lq * 4;
    #pragma unroll
    for (int r = 0; r < 4; ++r) {
      int lrow = mt * 128 + mb + r;
      if (lrow < Ne) {
        size_t hrow = (size_t)(rbase + lrow) * F_DIM;
        #pragma unroll
        for (int ni = 0; ni < 2; ++ni) {
          int f = nt * 128 + wn * 32 + ni * 16 + lr16;
          float a1v = acc1[mi][ni][r];
          float a3v = acc3[mi][ni][r];
          float hv = (a1v / (1.f + __expf(-a1v))) * a3v;
          H[hrow + f] = f2bf(hv);
        }
      }
    }
  }
}

// ---------------- GEMM2: Y = H @ w2^T (bf16 out)
// 512 threads (8 waves), BM=128 BN=64 BK=64; LDS 64KB, 2 blocks/CU -> 16 waves/CU.
__global__ __launch_bounds__(512, 4) void moe_gemm2(
    const unsigned short* __restrict__ H, const float* __restrict__ w2s,
    const int* __restrict__ cnt, const int* __restrict__ rowbase,
    unsigned short* __restrict__ Ybf)
{
  int e = blockIdx.z, mt = blockIdx.y, nt = blockIdx.x;
  int Ne = cnt[e];
  if (mt * 128 >= Ne) return;
  int rbase = rowbase[e];

  __shared__ char smem[65536];

  int tid = threadIdx.x, lane = tid & 63, wave = tid >> 6;

  // A staging: 16 chunks (8 rows x 128B); wave owns 2 chunks
  const char* pa[2];
  #pragma unroll
  for (int it = 0; it < 2; ++it) {
    int r = (wave * 2 + it) * 8 + (lane >> 3);
    int c = (lane & 7) ^ (r & 7);
    int grow = mt * 128 + r; if (grow >= Ne) grow = Ne - 1;
    pa[it] = (const char*)(H + (size_t)(rbase + grow) * F_DIM) + c * 16;
  }
  // B staging: 16 chunks (4 rows x 256B); wave owns 2 chunks
  const float* w2e = w2s + (size_t)e * D_DIM * F_DIM + (size_t)(nt * 64) * F_DIM;
  const char* pb[2];
  #pragma unroll
  for (int it = 0; it < 2; ++it) {
    int r = (wave * 2 + it) * 4 + (lane >> 4);
    int c = (lane & 15) ^ (r & 7);
    pb[it] = (const char*)(w2e + (size_t)r * F_DIM) + c * 16;
  }

  // 8 waves = 2M x 4N; wave-tile 64x16
  int wm = wave >> 2, wn = wave & 3;
  int lr16 = lane & 15, lq = lane >> 4;

  f32x4 acc[4];
  #pragma unroll
  for (int i = 0; i < 4; ++i) acc[i] = {0.f,0.f,0.f,0.f};

  unsigned dst = (unsigned)((wave * 2) * 1024 + lane * 16);

  auto STAGE = [&](unsigned bsel, int ks) {
    #pragma unroll
    for (int it = 0; it < 2; ++it) {
      gload16(pa[it] + ks * 128, smem + bsel * 16384 + dst + it * 1024);
      gload16(pb[it] + ks * 256, smem + 32768 + bsel * 16384 + dst + it * 1024);
    }
  };

  STAGE(0, 0);
  unsigned buf = 0;
  for (int ks = 0; ks < 64; ++ks) {
    if (ks < 63) {
      STAGE(buf ^ 1u, ks + 1);
      asm volatile("s_waitcnt vmcnt(4)" ::: "memory");
    } else {
      asm volatile("s_waitcnt vmcnt(0)" ::: "memory");
    }
    __builtin_amdgcn_s_barrier();
    unsigned ab = buf * 16384;
    unsigned bb = 32768 + buf * 16384;
    int n = wn * 16 + lr16;
    #pragma unroll
    for (int ksub = 0; ksub < 2; ++ksub) {
      bf16x8 bf;
      {
        unsigned o0 = (unsigned)(n * 256 + (((ksub * 8 + lq * 2 + 0) ^ (n & 7)) * 16));
        unsigned o1 = (unsigned)(n * 256 + (((ksub * 8 + lq * 2 + 1) ^ (n & 7)) * 16));
        bf = cvt8(*(const f32x4*)(smem + bb + o0), *(const f32x4*)(smem + bb + o1));
      }
      #pragma unroll
      for (int mi = 0; mi < 4; ++mi) {
        int m = wm * 64 + mi * 16 + lr16;
        unsigned off = (unsigned)(m * 128 + (((ksub * 4 + lq) ^ (m & 7)) * 16));
        bf16x8 af = *(const bf16x8*)(smem + ab + off);
        acc[mi] = __builtin_amdgcn_mfma_f32_16x16x32_bf16(af, bf, acc[mi], 0, 0, 0);
      }
    }
    __builtin_amdgcn_s_barrier();
    buf ^= 1u;
  }

  #pragma unroll
  for (int mi = 0; mi < 4; ++mi) {
    int mb = wm * 64 + mi * 16 + lq * 4;
    #pragma unroll
    for (int r = 0; r < 4; ++r) {
      int lrow = mt * 128 + mb + r;
      if (lrow < Ne) {
        size_t yrow = (size_t)(rbase + lrow) * D_DIM;
        int d = nt * 64 + wn * 16 + lr16;
        Ybf[yrow + d] = f2bf(acc[mi][r]);
      }
    }
  }
}

// ---------------- combine
__global__ __launch_bounds__(128) void moe_combine(
    const unsigned short* __restrict__ Ybf, const int* __restrict__ rowpos,
    const float* __restrict__ topw, float* __restrict__ out)
{
  int t = blockIdx.x, tid = threadIdx.x;
  int r0 = rowpos[t * 2], r1 = rowpos[t * 2 + 1];
  float p0 = topw[t * 2], p1 = topw[t * 2 + 1];
  uint4 a = ((const uint4*)(Ybf + (size_t)r0 * D_DIM))[tid];
  uint4 b = ((const uint4*)(Ybf + (size_t)r1 * D_DIM))[tid];
  float4 o0, o1;
  #define LO(u) __builtin_bit_cast(float, (unsigned)((u) << 16))
  #define HI(u) __builtin_bit_cast(float, (unsigned)((u) & 0xffff0000u))
  o0.x = p0 * LO(a.x) + p1 * LO(b.x);  o0.y = p0 * HI(a.x) + p1 * HI(b.x);
  o0.z = p0 * LO(a.y) + p1 * LO(b.y);  o0.w = p0 * HI(a.y) + p1 * HI(b.y);
  o1.x = p0 * LO(a.z) + p1 * LO(b.z);  o1.y = p0 * HI(a.z) + p1 * HI(b.z);
  o1.z = p0 * LO(a.w) + p1 * LO(b.w);  o1.w = p0 * HI(a.w) + p1 * HI(b.w);
  #undef LO
  #undef HI
  float4* orow = (float4*)(out + (size_t)t * D_DIM);
  orow[tid * 2]     = o0;
  orow[tid * 2 + 1] = o1;
}

extern "C" void kernel_launch(void* const* d_in, const int* in_sizes, int n_in,
                              void* d_out, int out_size, void* d_ws, size_t ws_size,
                              hipStream_t stream) {
  const float* x    = (const float*)d_in[0];
  const float* gate = (const float*)d_in[1];
  const float* w1   = (const float*)d_in[2];
  const float* w2   = (const float*)d_in[3];
  const float* w3   = (const float*)d_in[4];
  float* out    = (float*)d_out;
  float* logits = out + (size_t)T_NUM * D_DIM;

  char* ws = (char*)d_ws;
  int*   cnt     = (int*)(ws + 0);
  int*   rowbase = (int*)(ws + 64);
  int*   topi    = (int*)(ws + 1024);
  float* topw    = (float*)(ws + 1024 + 16384);
  int*   rowlist = (int*)(ws + 1024 + 32768);
  int*   rowpos  = (int*)(ws + 1024 + 49152);
  unsigned short* H   = (unsigned short*)(ws + 131072);                      // 32 MB
  unsigned short* Ybf = (unsigned short*)(ws + 131072 + 33554432);           // 8 MB
  unsigned short* xbf = (unsigned short*)(ws + 131072 + 33554432 + 8388608); // 4 MB

  moe_xcast<<<(T_NUM * D_DIM) / (256 * 8), 256, 0, stream>>>(x, xbf);
  moe_router<<<T_NUM / 16, 256, 0, stream>>>(x, gate, logits, topi, topw);
  moe_route_build<<<1, 1024, 0, stream>>>(topi, cnt, rowbase, rowlist, rowpos);
  moe_gemm1<<<dim3(F_DIM / 128, T_NUM / 128, E_NUM), 512, 0, stream>>>(xbf, w1, w3, cnt, rowbase, rowlist, H);
  moe_gemm2<<<dim3(D_DIM / 64, T_NUM / 128, E_NUM), 512, 0, stream>>>(H, w2, cnt, rowbase, Ybf);
  moe_combine<<<T_NUM, 128, 0, stream>>>(Ybf, rowpos, topw, out);
}